// Round 4
// baseline (84.354 us; speedup 1.0000x reference)
//
#include <hip/hip_runtime.h>

#define XX 36
#define XY 10
#define ROW 396               // XX * (XY + 1)
#define RPB 4                 // rows per block
#define BLK 256               // 4 waves -> 8 blocks/CU = 32 waves/CU
#define EPB (RPB * ROW)       // 1584 floats = 6336 B
#define V4  (EPB / 4)         // 396 float4
#define NG  (RPB * XX)        // 144 compute groups

typedef float f4 __attribute__((ext_vector_type(4)));
typedef float f2 __attribute__((ext_vector_type(2)));

__global__ __launch_bounds__(BLK, 8)
void lorenz96_fs_kernel(const float* __restrict__ u,
                        const float* __restrict__ param,
                        float* __restrict__ out) {
    __shared__ float si[EPB];   // input tile only
    const int tid = threadIdx.x;

    const float F = param[0];
    const float h = param[1];
    const float c = param[2];
    const float b = param[3];

    const long long base = (long long)blockIdx.x * EPB;

    // ---- stage 4 rows into LDS: nontemporal, coalesced 16B loads ----
    const f4* __restrict__ in4 = (const f4*)(u + base);
    f4* si4 = (f4*)si;
    si4[tid] = __builtin_nontemporal_load(&in4[tid]);
    if (tid < V4 - BLK) si4[tid + BLK] = __builtin_nontemporal_load(&in4[tid + BLK]);
    __syncthreads();

    // ---- one thread per (row, group): compute and store DIRECTLY ----
    if (tid < NG) {
        const int r = tid / XX;            // 0..3
        const int i = tid - r * XX;        // 0..35
        const float* __restrict__ row  = si + r * ROW;
        float*       __restrict__ orow = out + base + r * ROW;

        const float xi  = row[i];
        const float xp1 = row[(i + 1 < XX) ? i + 1 : i + 1 - XX];
        const float xm1 = row[(i >= 1) ? i - 1 : i + XX - 1];
        const float xm2 = row[(i >= 2) ? i - 2 : i + XX - 2];

        float y[XY];
        const float* __restrict__ yr = row + XX + i * XY;
        #pragma unroll
        for (int j = 0; j < XY; ++j) y[j] = yr[j];

        float sum = 0.0f;
        #pragma unroll
        for (int j = 0; j < XY; ++j) sum += y[j];

        const float dx = (xp1 - xm2) * xm1 - xi + F - (h * c * 0.1f) * sum;
        __builtin_nontemporal_store(dx, &orow[i]);

        const float add = h * 0.1f * xi;
        const float cb  = c * b;
        float dy[XY];
        #pragma unroll
        for (int j = 0; j < XY; ++j) {
            const int jp1 = (j + 1) % XY;          // compile-time under unroll
            const int jp2 = (j + 2) % XY;
            const int jm1 = (j + XY - 1) % XY;
            dy[j] = c * (add - y[j]) - cb * y[jp1] * (y[jp2] - y[jm1]);
        }

        // dy block starts at byte offset (36 + 10*i)*4: 8-aligned -> float2 ok
        f2* __restrict__ oy = (f2*)(orow + XX + i * XY);
        #pragma unroll
        for (int j = 0; j < XY / 2; ++j) {
            f2 v; v.x = dy[2 * j]; v.y = dy[2 * j + 1];
            __builtin_nontemporal_store(v, &oy[j]);
        }
    }
}

extern "C" void kernel_launch(void* const* d_in, const int* in_sizes, int n_in,
                              void* d_out, int out_size, void* d_ws, size_t ws_size,
                              hipStream_t stream) {
    // inputs: d_in[0] = t (int scalar, unused), d_in[1] = u (f32), d_in[2] = param (f32 x4)
    const float* u     = (const float*)d_in[1];
    const float* param = (const float*)d_in[2];
    float* out         = (float*)d_out;

    const int nrows   = in_sizes[1] / ROW;     // 131072
    const int nblocks = nrows / RPB;           // 32768

    lorenz96_fs_kernel<<<nblocks, BLK, 0, stream>>>(u, param, out);
}

// Round 5
// 76.214 us; speedup vs baseline: 1.1068x; 1.1068x over previous
//
#include <hip/hip_runtime.h>

#define XX 36
#define XY 10
#define ROW 396               // XX * (XY + 1)
#define RPB 4                 // rows per block = 1 row per wave
#define BLK 256               // 4 waves -> 8 blocks/CU = 32 waves/CU
#define EPB (RPB * ROW)       // 1584 floats = 6336 B per tile
#define RV4 (ROW / 4)         // 99 float4 per row

typedef float f4 __attribute__((ext_vector_type(4)));

// wave-local ordering fence: drain this wave's outstanding LDS ops and
// forbid compiler reordering across it. DS ops of one wave execute in
// order, so this replaces __syncthreads() for wave-private tiles.
#define WAVE_LDS_FENCE() asm volatile("s_waitcnt lgkmcnt(0)" ::: "memory")

__global__ __launch_bounds__(BLK, 8)
void lorenz96_fs_kernel(const float* __restrict__ u,
                        const float* __restrict__ param,
                        float* __restrict__ out) {
    __shared__ float si[EPB];   // input tiles,  one 396-float slice per wave
    __shared__ float so[EPB];   // output tiles, one 396-float slice per wave

    const int tid = threadIdx.x;
    const int w   = tid >> 6;          // wave id 0..3
    const int l   = tid & 63;          // lane

    const float F = param[0];
    const float h = param[1];
    const float c = param[2];
    const float b = param[3];

    const long long rowg = (long long)blockIdx.x * RPB + w;   // this wave's row
    const long long gbase = rowg * ROW;

    // ---- wave loads its row: 99 float4, coalesced ----
    const f4* __restrict__ in4 = (const f4*)(u + gbase);
    f4* si4 = (f4*)(si + w * ROW);
    si4[l] = in4[l];
    if (l < RV4 - 64) si4[l + 64] = in4[l + 64];

    WAVE_LDS_FENCE();

    // ---- lanes 0..35: one (group i) each -> dx[i] + dy[i][0..9] ----
    if (l < XX) {
        const int i = l;
        const float* __restrict__ row  = si + w * ROW;
        float*       __restrict__ orow = so + w * ROW;

        const float xi  = row[i];
        const float xp1 = row[(i + 1 < XX) ? i + 1 : i + 1 - XX];
        const float xm1 = row[(i >= 1) ? i - 1 : i + XX - 1];
        const float xm2 = row[(i >= 2) ? i - 2 : i + XX - 2];

        float y[XY];
        const float* __restrict__ yr = row + XX + i * XY;
        #pragma unroll
        for (int j = 0; j < XY; ++j) y[j] = yr[j];

        float sum = 0.0f;
        #pragma unroll
        for (int j = 0; j < XY; ++j) sum += y[j];

        orow[i] = (xp1 - xm2) * xm1 - xi + F - (h * c * 0.1f) * sum;

        const float add = h * 0.1f * xi;
        const float cb  = c * b;
        float* __restrict__ oyr = orow + XX + i * XY;
        #pragma unroll
        for (int j = 0; j < XY; ++j) {
            const int jp1 = (j + 1) % XY;          // compile-time under unroll
            const int jp2 = (j + 2) % XY;
            const int jm1 = (j + XY - 1) % XY;
            oyr[j] = c * (add - y[j]) - cb * y[jp1] * (y[jp2] - y[jm1]);
        }
    }

    WAVE_LDS_FENCE();

    // ---- wave stores its row: 99 float4, coalesced ----
    const f4* __restrict__ so4 = (const f4*)(so + w * ROW);
    f4* __restrict__ o4 = (f4*)(out + gbase);
    o4[l] = so4[l];
    if (l < RV4 - 64) o4[l + 64] = so4[l + 64];
}

extern "C" void kernel_launch(void* const* d_in, const int* in_sizes, int n_in,
                              void* d_out, int out_size, void* d_ws, size_t ws_size,
                              hipStream_t stream) {
    // inputs: d_in[0] = t (int scalar, unused), d_in[1] = u (f32), d_in[2] = param (f32 x4)
    const float* u     = (const float*)d_in[1];
    const float* param = (const float*)d_in[2];
    float* out         = (float*)d_out;

    const int nrows   = in_sizes[1] / ROW;     // 131072
    const int nblocks = nrows / RPB;           // 32768

    lorenz96_fs_kernel<<<nblocks, BLK, 0, stream>>>(u, param, out);
}

// Round 6
// 64.835 us; speedup vs baseline: 1.3011x; 1.1755x over previous
//
#include <hip/hip_runtime.h>

#define XX 36
#define XY 10
#define ROW 396               // XX * (XY + 1)
#define RPB 4                 // rows per block = 1 row per wave
#define BLK 256               // 4 waves -> 8 blocks/CU = 32 waves/CU
#define EPB (RPB * ROW)       // 1584 floats = 6336 B per tile
#define RV4 (ROW / 4)         // 99 float4 per row

typedef float f4 __attribute__((ext_vector_type(4)));

// wave-local ordering fence: drain this wave's outstanding LDS ops and
// forbid compiler reordering across it. DS ops of one wave execute in
// order, so this replaces __syncthreads() for wave-private tiles.
#define WAVE_LDS_FENCE() asm volatile("s_waitcnt lgkmcnt(0)" ::: "memory")

__global__ __launch_bounds__(BLK, 8)
void lorenz96_fs_kernel(const float* __restrict__ u,
                        const float* __restrict__ param,
                        float* __restrict__ out) {
    __shared__ float si[EPB];   // input tiles,  one 396-float slice per wave
    __shared__ float so[EPB];   // output tiles, one 396-float slice per wave

    const int tid = threadIdx.x;
    const int w   = tid >> 6;          // wave id 0..3
    const int l   = tid & 63;          // lane

    const float F = param[0];
    const float h = param[1];
    const float c = param[2];
    const float b = param[3];

    const long long rowg = (long long)blockIdx.x * RPB + w;   // this wave's row
    const long long gbase = rowg * ROW;

    // ---- wave loads its row: 99 float4, coalesced, CACHED (L3-resident) ----
    const f4* __restrict__ in4 = (const f4*)(u + gbase);
    f4* si4 = (f4*)(si + w * ROW);
    si4[l] = in4[l];
    if (l < RV4 - 64) si4[l + 64] = in4[l + 64];

    WAVE_LDS_FENCE();

    // ---- lanes 0..35: one (group i) each -> dx[i] + dy[i][0..9] ----
    if (l < XX) {
        const int i = l;
        const float* __restrict__ row  = si + w * ROW;
        float*       __restrict__ orow = so + w * ROW;

        const float xi  = row[i];
        const float xp1 = row[(i + 1 < XX) ? i + 1 : i + 1 - XX];
        const float xm1 = row[(i >= 1) ? i - 1 : i + XX - 1];
        const float xm2 = row[(i >= 2) ? i - 2 : i + XX - 2];

        float y[XY];
        const float* __restrict__ yr = row + XX + i * XY;
        #pragma unroll
        for (int j = 0; j < XY; ++j) y[j] = yr[j];

        float sum = 0.0f;
        #pragma unroll
        for (int j = 0; j < XY; ++j) sum += y[j];

        orow[i] = (xp1 - xm2) * xm1 - xi + F - (h * c * 0.1f) * sum;

        const float add = h * 0.1f * xi;
        const float cb  = c * b;
        float* __restrict__ oyr = orow + XX + i * XY;
        #pragma unroll
        for (int j = 0; j < XY; ++j) {
            const int jp1 = (j + 1) % XY;          // compile-time under unroll
            const int jp2 = (j + 2) % XY;
            const int jm1 = (j + XY - 1) % XY;
            oyr[j] = c * (add - y[j]) - cb * y[jp1] * (y[jp2] - y[jm1]);
        }
    }

    WAVE_LDS_FENCE();

    // ---- wave stores its row: 99 float4, coalesced, NONTEMPORAL ----
    // NT on stores only: keep the output stream from evicting the
    // L3-resident input stream. (Round 4 wrongly NT'd the loads too.)
    const f4* __restrict__ so4 = (const f4*)(so + w * ROW);
    f4* __restrict__ o4 = (f4*)(out + gbase);
    __builtin_nontemporal_store(so4[l], &o4[l]);
    if (l < RV4 - 64) __builtin_nontemporal_store(so4[l + 64], &o4[l + 64]);
}

extern "C" void kernel_launch(void* const* d_in, const int* in_sizes, int n_in,
                              void* d_out, int out_size, void* d_ws, size_t ws_size,
                              hipStream_t stream) {
    // inputs: d_in[0] = t (int scalar, unused), d_in[1] = u (f32), d_in[2] = param (f32 x4)
    const float* u     = (const float*)d_in[1];
    const float* param = (const float*)d_in[2];
    float* out         = (float*)d_out;

    const int nrows   = in_sizes[1] / ROW;     // 131072
    const int nblocks = nrows / RPB;           // 32768

    lorenz96_fs_kernel<<<nblocks, BLK, 0, stream>>>(u, param, out);
}